// Round 20
// baseline (54.159 us; speedup 1.0000x reference)
//
#include <hip/hip_runtime.h>

// Problem constants (from reference)
#define NS   1000        // N_SAMPLES
#define NB   32          // batch
#define NK   27          // cluster channels
#define KP   28          // padded K (for float4)
#define HW   65536       // 256*256
// sim = 10*exp(-cd/1.0 - gd/0.3) + 3*exp(-10*cd)
// SPARSITY (validated R13/R14): cd >= 30 => sim underflows (|masked| <= ~1e-9
// << threshold 16.88) => emit exact 0, skip all data access (99.7% of pairs).
// R20: R19 + wave-ballot gate on the per-row uniform a-data loads (skip the
// 8 dependent s_load chains for ~50% of (wave,row) pairs).

// ws layout (floats):
//   selc [NB][NS][KP]  : 896000
//   selg [NB][NS][4]   : 128000   (offset 896000)
//   cf   [NS][2]       : 2000     (offset 1024000)
#define OFF_SELG 896000
#define OFF_CF   1024000

typedef __attribute__((ext_vector_type(4))) float f32x4;

// gather: one thread per (n, i, ch), ch in [0,32)  (R10 verbatim)
__global__ void crf_gather(const float* __restrict__ guidance,
                           const float* __restrict__ clusters,
                           const int* __restrict__ coords,
                           float* __restrict__ ws) {
    int tid = blockIdx.x * 256 + threadIdx.x;
    if (tid >= NB * NS * 32) return;
    int ch = tid & 31;
    int ni = tid >> 5;
    int n = ni / NS;
    int i = ni - n * NS;
    int r = coords[i];
    int c = coords[NS + i];
    int pix = r * 256 + c;

    if (ch < KP) {
        float v = 0.0f;
        if (ch < NK)
            v = clusters[((long)n * NK + ch) * HW + pix];
        ws[(long)ni * KP + ch] = v;
    } else {
        int g = ch - KP;  // 0..3
        float v = 0.0f;
        if (g < 3)
            v = guidance[((long)n * 3 + g) * HW + pix];
        ws[OFF_SELG + (long)ni * 4 + g] = v;
        if (g == 3 && n == 0) {
            ws[OFF_CF + i * 2]     = (float)r;
            ws[OFF_CF + i * 2 + 1] = (float)c;
        }
    }
}

#define RA     10          // a-rows per block
#define NCHUNK 100         // NS / RA

// main: block = (n, 10 a-rows); 256 threads; thread t<250 owns b = 4t..4t+3,
// ONE f32x4 store per row. Per-row uniform a-data loads gated on wave ballot.
__global__ __launch_bounds__(256) void crf_main(const float* __restrict__ ws,
                                                float* __restrict__ out) {
    const int bid = blockIdx.x;
    const int n = bid / NCHUNK;
    const int a0 = (bid - n * NCHUNK) * RA;
    const int t = threadIdx.x;

    const float* __restrict__ selc = ws;
    const float* __restrict__ selg = ws + OFF_SELG;
    const float* __restrict__ cf   = ws + OFF_CF;

    const bool act = (t < 250);
    const int b4 = 4 * t;                    // 0..996

    float xbr[4], xbc[4];
    {
        const int bq = act ? b4 : 996;
        #pragma unroll
        for (int j = 0; j < 4; ++j) {
            xbr[j] = cf[2 * (bq + j)];
            xbc[j] = cf[2 * (bq + j) + 1];
        }
    }

    // hoist all RA rows' coords (wave-uniform, contiguous 20 floats)
    float xars[RA], xacs[RA];
    #pragma unroll
    for (int a = 0; a < RA; ++a) {
        xars[a] = cf[2 * (a0 + a)];
        xacs[a] = cf[2 * (a0 + a) + 1];
    }

    #pragma unroll
    for (int a = 0; a < RA; ++a) {
        const int ai = a0 + a;
        const long arow = (long)n * NS + ai;
        const float xar = xars[a], xac = xacs[a];

        // per-lane gate for the 4 owned columns (cheap VALU, no loads)
        float cd[4];
        bool any = false;
        #pragma unroll
        for (int j = 0; j < 4; ++j) {
            float dr = xar - xbr[j], dc = xac - xbc[j];
            cd[j] = dr * dr + dc * dc;
            any |= (cd[j] < 30.0f);
        }
        any &= act;

        f32x4 res = {0.0f, 0.0f, 0.0f, 0.0f};
        if (__builtin_amdgcn_ballot_w64(any)) {
            // at least one lane in this wave computes -> load uniform a-data
            const float4* pa4 = (const float4*)(selc + arow * KP);
            float4 pa[7];
            #pragma unroll
            for (int j = 0; j < 7; ++j) pa[j] = pa4[j];
            const float* pga = selg + arow * 4;
            const float ga0 = pga[0], ga1 = pga[1], ga2 = pga[2];

            if (any) {
                #pragma unroll
                for (int j = 0; j < 4; ++j) {
                    if (cd[j] < 30.0f) {
                        const long brow = (long)n * NS + b4 + j;
                        const float4* pb4 = (const float4*)(selc + brow * KP);
                        float dot = 0.0f;
                        #pragma unroll
                        for (int q = 0; q < 7; ++q) {
                            float4 va = pa[q], vb = pb4[q];
                            dot += va.x * vb.x;
                            dot += va.y * vb.y;
                            dot += va.z * vb.z;
                            dot += va.w * vb.w;
                        }
                        const float* pgb = selg + brow * 4;
                        float g0 = ga0 - pgb[0];
                        float g1 = ga1 - pgb[1];
                        float g2 = ga2 - pgb[2];
                        float gd = g0 * g0 + g1 * g1 + g2 * g2;
                        float s = 10.0f * __expf(-cd[j] - gd * (1.0f / 0.3f))
                                +  3.0f * __expf(-10.0f * cd[j]);
                        res[j] = -dot * s;
                    }
                }
            }
        }
        if (act)
            *(f32x4*)(out + arow * NS + b4) = res;
    }
}

extern "C" void kernel_launch(void* const* d_in, const int* in_sizes, int n_in,
                              void* d_out, int out_size, void* d_ws, size_t ws_size,
                              hipStream_t stream) {
    const float* guidance = (const float*)d_in[0];
    const float* clusters = (const float*)d_in[1];
    const int*   coords   = (const int*)d_in[2];
    float* out = (float*)d_out;
    float* ws  = (float*)d_ws;

    {
        int total = NB * NS * 32;
        int blocks = (total + 255) / 256;
        crf_gather<<<blocks, 256, 0, stream>>>(guidance, clusters, coords, ws);
    }
    {
        int blocks = NB * NCHUNK;   // 3200
        crf_main<<<blocks, 256, 0, stream>>>(ws, out);
    }
}

// Round 21
// 52.846 us; speedup vs baseline: 1.0248x; 1.0248x over previous
//
#include <hip/hip_runtime.h>

// Problem constants (from reference)
#define NS   1000        // N_SAMPLES
#define NB   32          // batch
#define NK   27          // cluster channels
#define KP   28          // padded K (for float4)
#define HW   65536       // 256*256
// sim = 10*exp(-cd/1.0 - gd/0.3) + 3*exp(-10*cd)
// SPARSITY (validated R13/R14): cd >= 30 => sim underflows (|masked| <= ~1e-9
// << threshold 16.88) => emit exact 0, skip all data access (99.7% of pairs).
// R21: R19 + RA=5 (6400 blocks, imbalance 1.02x) + compute-then-store batching
// (5 back-to-back f32x4 stores per thread; uninterrupted store burst).

// ws layout (floats):
//   selc [NB][NS][KP]  : 896000
//   selg [NB][NS][4]   : 128000   (offset 896000)
//   cf   [NS][2]       : 2000     (offset 1024000)
#define OFF_SELG 896000
#define OFF_CF   1024000

typedef __attribute__((ext_vector_type(4))) float f32x4;

// gather: one thread per (n, i, ch), ch in [0,32)  (R10 verbatim)
__global__ void crf_gather(const float* __restrict__ guidance,
                           const float* __restrict__ clusters,
                           const int* __restrict__ coords,
                           float* __restrict__ ws) {
    int tid = blockIdx.x * 256 + threadIdx.x;
    if (tid >= NB * NS * 32) return;
    int ch = tid & 31;
    int ni = tid >> 5;
    int n = ni / NS;
    int i = ni - n * NS;
    int r = coords[i];
    int c = coords[NS + i];
    int pix = r * 256 + c;

    if (ch < KP) {
        float v = 0.0f;
        if (ch < NK)
            v = clusters[((long)n * NK + ch) * HW + pix];
        ws[(long)ni * KP + ch] = v;
    } else {
        int g = ch - KP;  // 0..3
        float v = 0.0f;
        if (g < 3)
            v = guidance[((long)n * 3 + g) * HW + pix];
        ws[OFF_SELG + (long)ni * 4 + g] = v;
        if (g == 3 && n == 0) {
            ws[OFF_CF + i * 2]     = (float)r;
            ws[OFF_CF + i * 2 + 1] = (float)c;
        }
    }
}

#define RA     5           // a-rows per block
#define NCHUNK 200         // NS / RA

// main: block = (n, 5 a-rows); 256 threads; thread t<250 owns b = 4t..4t+3.
// Phase 1: compute res[5] (gated, lazy loads). Phase 2: 5 f32x4 stores
// back-to-back.
__global__ __launch_bounds__(256) void crf_main(const float* __restrict__ ws,
                                                float* __restrict__ out) {
    const int bid = blockIdx.x;
    const int n = bid / NCHUNK;
    const int a0 = (bid - n * NCHUNK) * RA;
    const int t = threadIdx.x;

    const float* __restrict__ selc = ws;
    const float* __restrict__ selg = ws + OFF_SELG;
    const float* __restrict__ cf   = ws + OFF_CF;

    const bool act = (t < 250);
    const int b4 = act ? 4 * t : 996;        // 0..996

    float xbr[4], xbc[4];
    #pragma unroll
    for (int j = 0; j < 4; ++j) {
        xbr[j] = cf[2 * (b4 + j)];
        xbc[j] = cf[2 * (b4 + j) + 1];
    }

    // hoist all RA rows' coords (wave-uniform, contiguous floats)
    float xars[RA], xacs[RA];
    #pragma unroll
    for (int a = 0; a < RA; ++a) {
        xars[a] = cf[2 * (a0 + a)];
        xacs[a] = cf[2 * (a0 + a) + 1];
    }

    f32x4 res[RA];

    // ---- phase 1: compute ----
    #pragma unroll
    for (int a = 0; a < RA; ++a) {
        const int ai = a0 + a;
        const long arow = (long)n * NS + ai;
        const float xar = xars[a], xac = xacs[a];

        // uniform a-row data (scalarized by compiler; hidden by TLP — R20)
        const float4* pa4 = (const float4*)(selc + arow * KP);
        float4 pa[7];
        #pragma unroll
        for (int j = 0; j < 7; ++j) pa[j] = pa4[j];
        const float* pga = selg + arow * 4;
        const float ga0 = pga[0], ga1 = pga[1], ga2 = pga[2];

        f32x4 r4 = {0.0f, 0.0f, 0.0f, 0.0f};
        #pragma unroll
        for (int j = 0; j < 4; ++j) {
            float dr = xar - xbr[j], dc = xac - xbc[j];
            float cd = dr * dr + dc * dc;
            if (cd < 30.0f) {
                const long brow = (long)n * NS + b4 + j;
                const float4* pb4 = (const float4*)(selc + brow * KP);
                float dot = 0.0f;
                #pragma unroll
                for (int q = 0; q < 7; ++q) {
                    float4 va = pa[q], vb = pb4[q];
                    dot += va.x * vb.x;
                    dot += va.y * vb.y;
                    dot += va.z * vb.z;
                    dot += va.w * vb.w;
                }
                const float* pgb = selg + brow * 4;
                float g0 = ga0 - pgb[0];
                float g1 = ga1 - pgb[1];
                float g2 = ga2 - pgb[2];
                float gd = g0 * g0 + g1 * g1 + g2 * g2;
                float s = 10.0f * __expf(-cd - gd * (1.0f / 0.3f))
                        +  3.0f * __expf(-10.0f * cd);
                r4[j] = -dot * s;
            }
        }
        res[a] = r4;
    }

    // ---- phase 2: store burst ----
    if (act) {
        float* po = out + ((long)n * NS + a0) * NS + b4;
        #pragma unroll
        for (int a = 0; a < RA; ++a)
            *(f32x4*)(po + (long)a * NS) = res[a];
    }
}

extern "C" void kernel_launch(void* const* d_in, const int* in_sizes, int n_in,
                              void* d_out, int out_size, void* d_ws, size_t ws_size,
                              hipStream_t stream) {
    const float* guidance = (const float*)d_in[0];
    const float* clusters = (const float*)d_in[1];
    const int*   coords   = (const int*)d_in[2];
    float* out = (float*)d_out;
    float* ws  = (float*)d_ws;

    {
        int total = NB * NS * 32;
        int blocks = (total + 255) / 256;
        crf_gather<<<blocks, 256, 0, stream>>>(guidance, clusters, coords, ws);
    }
    {
        int blocks = NB * NCHUNK;   // 6400
        crf_main<<<blocks, 256, 0, stream>>>(ws, out);
    }
}